// Round 13
// baseline (1926.040 us; speedup 1.0000x reference)
//
#include <hip/hip_runtime.h>
#include <math.h>

#define NPTS 1024
#define CAND 224
#define KEFF 64
#define BATCH 2
#define NEGV -1e30f
#define PLANE (BATCH * NPTS * CAND)

struct KP {
    const float* x;
    const float* w0; const float* w1; const float* w2; const float* w3;
    const float* g0; const float* g1; const float* g2; const float* g3;
    const float* b0; const float* b1; const float* b2; const float* b3;
    const float* wl;
    float* xconM; float* A; float* Bv; float* sqv; float* Dp; float* part; float* wt;
    int* idx; int* bar; float* out;
};

// ---------------- device-scope barrier (monotone counter; poll with atomic LOAD, not CAS —
// CAS takes exclusive cacheline ownership per poll and serialized 512 spinners at ~120us/barrier in R12)
__device__ __forceinline__ void gsync(int* bar, int& phase, int G) {
    ++phase;
    __threadfence();
    __syncthreads();
    if (threadIdx.x == 0) {
        __hip_atomic_fetch_add(bar, 1, __ATOMIC_ACQ_REL, __HIP_MEMORY_SCOPE_AGENT);
        int target = phase * G;
        while (__hip_atomic_load(bar, __ATOMIC_ACQUIRE, __HIP_MEMORY_SCOPE_AGENT) < target)
            __builtin_amdgcn_s_sleep(32);
    }
    __syncthreads();
    __threadfence();
}

// ---------------- prep: weight transpose, 204 work items
__device__ __forceinline__ void prep_body(int id, const KP& p, float* smem) {
    int t = threadIdx.x;
    float* tA = smem;
    float* tB = smem + 1056;
    int row = t >> 5, col = t & 31;
    const float* W = p.w0; int Cin = 256, Co = 128; float* WtA = p.wt; float* WtB = p.wt + 32768;
    int tc = 0, to = 0; bool isWL = false;
    if (id < 32)      { int r = id;      tc = r >> 2; to = r & 3; }
    else if (id < 48) { W = p.w1; Cin = 128; Co = 128; WtA = p.wt + 65536;  WtB = p.wt + 81920;  int r = id - 32; tc = r >> 2; to = r & 3; }
    else if (id < 56) { W = p.w2; Cin = 128; Co = 64;  WtA = p.wt + 98304;  WtB = p.wt + 106496; int r = id - 48; tc = r >> 1; to = r & 1; }
    else if (id < 60) { W = p.w3; Cin = 64;  Co = 64;  WtA = p.wt + 114688; WtB = p.wt + 118784; int r = id - 56; tc = r >> 1; to = r & 1; }
    else { isWL = true; int r = id - 60; tc = r / 12; to = r % 12; }
    if (!isWL) {
#pragma unroll
        for (int r = 0; r < 4; ++r) {
            int o = to * 32 + row + r * 8;
            int c = tc * 32 + col;
            float va = W[(size_t)o * 2 * Cin + c];
            tA[(row + r * 8) * 33 + col] = va;
            tB[(row + r * 8) * 33 + col] = W[(size_t)o * 2 * Cin + Cin + c] - va;
        }
        __syncthreads();
#pragma unroll
        for (int r = 0; r < 4; ++r) {
            int c = tc * 32 + row + r * 8;
            int o = to * 32 + col;
            WtA[(size_t)c * Co + o] = tA[col * 33 + row + r * 8];
            WtB[(size_t)c * Co + o] = tB[col * 33 + row + r * 8];
        }
    } else {
        float* wlT = p.wt + 122880;
#pragma unroll
        for (int r = 0; r < 4; ++r) {
            int o = to * 32 + row + r * 8;
            int c = tc * 32 + col;
            tA[(row + r * 8) * 33 + col] = p.wl[(size_t)o * 384 + c];
        }
        __syncthreads();
#pragma unroll
        for (int r = 0; r < 4; ++r) {
            int c = tc * 32 + row + r * 8;
            int o = to * 32 + col;
            wlT[(size_t)c * 384 + o] = tA[col * 33 + row + r * 8];
        }
    }
}

// ---------------- select: top-64 rank keys, 512 work items
template<int NCH>
__device__ __forceinline__ void select_body(int wk, const KP& p, float* smemf) {
    unsigned long long* Dsh = (unsigned long long*)smemf;
    int t = threadIdx.x;
    int wv = t >> 6, l = t & 63;
    int b = wk >> 8;
    int n = (wk & 255) * 4 + wv;
    int i = n >> 5;
    float sqn = p.sqv[b * NPTS + n];
    float pr[4][NCH];
    float sqw[4];
#pragma unroll
    for (int j = 0; j < 4; ++j) {
        int w = l + 64 * j;
        if (w < CAND) {
            size_t off = ((size_t)b * NPTS + n) * CAND + w;
#pragma unroll
            for (int ch = 0; ch < NCH; ++ch)
                pr[j][ch] = p.Dp[off + (size_t)ch * PLANE];
            int wb = i - 3 + (w >> 5);
            int wbc = wb < 0 ? 0 : (wb > 31 ? 31 : wb);
            sqw[j] = p.sqv[b * NPTS + wbc * 32 + (w & 31)];
        }
    }
    unsigned long long kj[4];
#pragma unroll
    for (int j = 0; j < 4; ++j) {
        int w = l + 64 * j;
        if (w < CAND) {
            float s = 0.f;
#pragma unroll
            for (int ch = 0; ch < NCH; ++ch) s += pr[j][ch];
            int wb = i - 3 + (w >> 5);
            bool valid = (wb >= 0) && (wb < 32);
            float d = 2.f * s - sqn - sqw[j];
            d = valid ? d : NEGV;
            unsigned u = __float_as_uint(d);
            u ^= ((unsigned)((int)u >> 31)) | 0x80000000u;
            unsigned long long key = ((unsigned long long)u << 8) | (unsigned long long)(255 - w);
            kj[j] = key;
            Dsh[wv * 224 + w] = key;
        } else {
            kj[j] = 0ull;
        }
    }
    __syncthreads();
    int cnt[4] = {0, 0, 0, 0};
    const ulonglong2* row = (const ulonglong2*)(Dsh + wv * 224);
#pragma unroll 2
    for (int w2 = 0; w2 < 112; w2 += 4) {
        ulonglong2 k0 = row[w2], k1 = row[w2 + 1], k2 = row[w2 + 2], k3 = row[w2 + 3];
#pragma unroll
        for (int j = 0; j < 4; ++j) {
            unsigned long long kk = kj[j];
            cnt[j] += (int)(k0.x > kk) + (int)(k0.y > kk) + (int)(k1.x > kk) + (int)(k1.y > kk)
                    + (int)(k2.x > kk) + (int)(k2.y > kk) + (int)(k3.x > kk) + (int)(k3.y > kk);
        }
    }
#pragma unroll
    for (int j = 0; j < 4; ++j) {
        int w = l + 64 * j;
        if (w < CAND && cnt[j] < KEFF)
            p.idx[((size_t)b * KEFF + cnt[j]) * NPTS + n] = (i - 3) * 32 + w;   // k-major
    }
}

// ---------------- agg: gather + max/S1/S2
template<int CO, int CHOUT>
__device__ __forceinline__ void agg_body(int wk, const KP& p, float* partOut, float* smem) {
    int t = threadIdx.x;
    int o = wk % CO, b = wk / CO;
    float* Ash = smem;
    float* red = smem + 1024;
    size_t rowoff = ((size_t)(b * CO + o)) * NPTS;
    {
        float rA[4];
#pragma unroll
        for (int r = 0; r < 4; ++r) rA[r] = p.A[rowoff + r * 256 + t];
#pragma unroll
        for (int r = 0; r < 4; ++r) Ash[r * 256 + t] = rA[r];
    }
    __syncthreads();
    float sum = 0.f, sumsq = 0.f;
    for (int r = 0; r < 4; ++r) {
        int n = r * 256 + t;
        const int* ip = p.idx + (size_t)b * KEFF * NPTS + n;
        float s1 = 0.f, s2 = 0.f, mx = -3.4e38f;
#pragma unroll
        for (int kb = 0; kb < 4; ++kb) {
            int iv[16];
#pragma unroll
            for (int m = 0; m < 16; ++m)
                iv[m] = ip[(size_t)(kb * 16 + m) * NPTS];
            float av[16];
#pragma unroll
            for (int m = 0; m < 16; ++m) av[m] = Ash[iv[m]];
#pragma unroll
            for (int m = 0; m < 16; m += 4) {
                s1 += av[m] + av[m+1] + av[m+2] + av[m+3];
                s2 += av[m]*av[m] + av[m+1]*av[m+1] + av[m+2]*av[m+2] + av[m+3]*av[m+3];
                mx = fmaxf(mx, fmaxf(fmaxf(av[m], av[m+1]), fmaxf(av[m+2], av[m+3])));
            }
        }
        float bv = p.Bv[rowoff + n];
        p.xconM[((size_t)b * 384 + CHOUT + o) * NPTS + n] = mx + bv;
        sum   += s1 + 64.f * bv;
        sumsq += s2 + 2.f * bv * s1 + 64.f * bv * bv;
    }
    red[t] = sum; __syncthreads();
    for (int s = 128; s > 0; s >>= 1) { if (t < s) red[t] += red[t + s]; __syncthreads(); }
    if (t == 0) partOut[((size_t)(b * CO + o)) * 2 + 0] = red[0];
    __syncthreads();
    red[t] = sumsq; __syncthreads();
    for (int s = 128; s > 0; s >>= 1) { if (t < s) red[t] += red[t + s]; __syncthreads(); }
    if (t == 0) partOut[((size_t)(b * CO + o)) * 2 + 1] = red[0];
}

// ---------------- final GEMM body, 192 work items
__device__ __forceinline__ void final_body(int wk, const KP& p, float* smem,
                                           const float* sc, const float* sh) {
    int t = threadIdx.x;
    float* Xs = smem;
    float* Wl = smem + 2048;
    const float* wlT = p.wt + 122880;
    int tn4 = (t & 15) * 4, to4 = (t >> 4) * 4;
    int n0 = (wk & 15) * 64;
    int o0 = ((wk >> 4) % 6) * 64;
    int b  = wk / 96;
    int cc0 = t >> 6, nn0 = t & 63;
    float4 acc[4];
#pragma unroll
    for (int i = 0; i < 4; ++i) acc[i] = make_float4(0.f,0.f,0.f,0.f);
    for (int c0 = 0; c0 < 384; c0 += 32) {
        float rx[8], rw[8];
#pragma unroll
        for (int k = 0; k < 8; ++k) {
            int cc = cc0 + k * 4;
            rx[k] = p.xconM[((size_t)b * 384 + c0 + cc) * NPTS + n0 + nn0];
            rw[k] = wlT[(size_t)(c0 + cc) * 384 + o0 + nn0];
        }
#pragma unroll
        for (int k = 0; k < 8; ++k) {
            int cc = cc0 + k * 4;
            float y = fmaf(rx[k], sc[c0 + cc], sh[c0 + cc]);
            rx[k] = y >= 0.f ? y : 0.2f * y;
        }
        __syncthreads();
#pragma unroll
        for (int k = 0; k < 8; ++k) {
            int cc = cc0 + k * 4;
            Xs[cc * 64 + nn0] = rx[k];
            Wl[cc * 68 + nn0] = rw[k];
        }
        __syncthreads();
#pragma unroll 4
        for (int cc = 0; cc < 32; ++cc) {
            float4 xv = *(const float4*)&Xs[cc * 64 + tn4];
            float4 wv = *(const float4*)&Wl[cc * 68 + to4];
            float wvv[4] = {wv.x, wv.y, wv.z, wv.w};
#pragma unroll
            for (int i = 0; i < 4; ++i) {
                acc[i].x = fmaf(wvv[i], xv.x, acc[i].x);
                acc[i].y = fmaf(wvv[i], xv.y, acc[i].y);
                acc[i].z = fmaf(wvv[i], xv.z, acc[i].z);
                acc[i].w = fmaf(wvv[i], xv.w, acc[i].w);
            }
        }
    }
#pragma unroll
    for (int i = 0; i < 4; ++i)
        *(float4*)&p.out[((size_t)b * 384 + o0 + to4 + i) * NPTS + n0 + tn4] = acc[i];
}

// ---------------- one layer: gemm+gram, select, agg; gsync between phases
template<int CIN, int CO, int NCH, int CHOUT, bool BN>
__device__ void layer_run(const KP& p, const float* __restrict__ xin, int bstride,
                          const float* __restrict__ wtA, const float* __restrict__ wtB,
                          const float* __restrict__ partPrev, const float* __restrict__ gP,
                          const float* __restrict__ beP, float* __restrict__ partOut,
                          float* smem, float* shsc, float* shsh, int& phase) {
    int t = threadIdx.x;
    const int G = gridDim.x;
    if (BN && t < CIN) {
        float s  = partPrev[t * 2]     + partPrev[(CIN + t) * 2];
        float s2 = partPrev[t * 2 + 1] + partPrev[(CIN + t) * 2 + 1];
        const float invc = 1.f / 131072.f;
        float mu = s * invc;
        float var = s2 * invc - mu * mu;
        float rs = rsqrtf(var + 1e-5f);
        float sc = gP[t] * rs;
        shsc[t] = sc;
        shsh[t] = beP[t] - mu * sc;
    }
    constexpr int nOT = CO >> 6;
    constexpr int nAB = 32 * nOT * BATCH;
    constexpr int nDist = NCH * 32 * BATCH;
    for (int wk = blockIdx.x; wk < nAB + nDist; wk += G) {
        __syncthreads();
        if (wk < nAB) {
            int nt = wk & 31; int rest = wk >> 5;
            int ot = rest % nOT; int b = rest / nOT;
            int tn2 = (t & 15) * 2, to4 = (t >> 4) * 4;
            int n0 = nt * 32, o0 = ot * 64;
            const float* xb = xin + (size_t)b * bstride + n0;
            float* Xs = smem; float* Wta = smem + 1024; float* Wtb = smem + 3200;
            float2 a2[4], b2[4], s2v;
#pragma unroll
            for (int i = 0; i < 4; ++i) { a2[i] = make_float2(0.f,0.f); b2[i] = make_float2(0.f,0.f); }
            s2v = make_float2(0.f,0.f);
            int xcc0 = t >> 5, xnn = t & 31;
            int wcc0 = t >> 6, woo = t & 63;
            for (int c0 = 0; c0 < CIN; c0 += 32) {
                float rx[4], ra[8], rb[8];
#pragma unroll
                for (int k = 0; k < 4; ++k)
                    rx[k] = xb[(size_t)(c0 + xcc0 + k * 8) * NPTS + xnn];
#pragma unroll
                for (int k = 0; k < 8; ++k) {
                    ra[k] = wtA[(size_t)(c0 + wcc0 + k * 4) * CO + o0 + woo];
                    rb[k] = wtB[(size_t)(c0 + wcc0 + k * 4) * CO + o0 + woo];
                }
                if (BN) {
#pragma unroll
                    for (int k = 0; k < 4; ++k) {
                        int cc = xcc0 + k * 8;
                        float y = fmaf(rx[k], shsc[c0 + cc], shsh[c0 + cc]);
                        rx[k] = y >= 0.f ? y : 0.2f * y;
                    }
                }
                __syncthreads();
#pragma unroll
                for (int k = 0; k < 4; ++k)
                    Xs[(xcc0 + k * 8) * 32 + xnn] = rx[k];
#pragma unroll
                for (int k = 0; k < 8; ++k) {
                    Wta[(wcc0 + k * 4) * 68 + woo] = ra[k];
                    Wtb[(wcc0 + k * 4) * 68 + woo] = rb[k];
                }
                __syncthreads();
#pragma unroll 8
                for (int cc = 0; cc < 32; ++cc) {
                    float2 xv = *(const float2*)&Xs[cc * 32 + tn2];
                    float4 wa = *(const float4*)&Wta[cc * 68 + to4];
                    float4 wb = *(const float4*)&Wtb[cc * 68 + to4];
                    s2v.x = fmaf(xv.x, xv.x, s2v.x);
                    s2v.y = fmaf(xv.y, xv.y, s2v.y);
                    float wav[4] = {wa.x, wa.y, wa.z, wa.w};
                    float wbv[4] = {wb.x, wb.y, wb.z, wb.w};
#pragma unroll
                    for (int i = 0; i < 4; ++i) {
                        a2[i].x = fmaf(wav[i], xv.x, a2[i].x);
                        a2[i].y = fmaf(wav[i], xv.y, a2[i].y);
                        b2[i].x = fmaf(wbv[i], xv.x, b2[i].x);
                        b2[i].y = fmaf(wbv[i], xv.y, b2[i].y);
                    }
                }
            }
            int n = n0 + tn2;
            if (ot == 0 && to4 == 0)
                *(float2*)&p.sqv[b * NPTS + n] = s2v;
#pragma unroll
            for (int i = 0; i < 4; ++i) {
                int o = o0 + to4 + i;
                size_t off = ((size_t)(b * CO + o)) * NPTS + n;
                *(float2*)&p.A[off] = a2[i];
                *(float2*)&p.Bv[off] = b2[i];
            }
        } else {
            int id2 = wk - nAB;
            int chunk = id2 % NCH; int rest = id2 / NCH;
            int i = rest & 31; int b = rest >> 5;
            int c0 = chunk * 32;
            const float* xb = xin + (size_t)b * bstride;
            float* Xc = smem;
            int q = t >> 3;
            int wg = t & 7;
            float r[28];
            int rcc[28], rw[28];
#pragma unroll
            for (int k = 0; k < 28; ++k) {
                int e = t + k * 256;
                int cc = e / CAND;
                int w  = e - cc * CAND;
                rcc[k] = cc; rw[k] = w;
                int wb = i - 3 + (w >> 5);
                wb = wb < 0 ? 0 : (wb > 31 ? 31 : wb);
                r[k] = xb[(size_t)(c0 + cc) * NPTS + wb * 32 + (w & 31)];
            }
            if (BN) {
#pragma unroll
                for (int k = 0; k < 28; ++k) {
                    float y = fmaf(r[k], shsc[c0 + rcc[k]], shsh[c0 + rcc[k]]);
                    r[k] = y >= 0.f ? y : 0.2f * y;
                }
            }
#pragma unroll
            for (int k = 0; k < 28; ++k)
                Xc[rcc[k] * CAND + rw[k]] = r[k];
            __syncthreads();
            float acc[28];
#pragma unroll
            for (int j = 0; j < 28; ++j) acc[j] = 0.f;
            for (int cc = 0; cc < 32; ++cc) {
                float qv = Xc[cc * CAND + 96 + q];
                const float4* row = (const float4*)&Xc[cc * CAND + wg * 28];
#pragma unroll
                for (int j4 = 0; j4 < 7; ++j4) {
                    float4 v = row[j4];
                    acc[j4 * 4 + 0] = fmaf(qv, v.x, acc[j4 * 4 + 0]);
                    acc[j4 * 4 + 1] = fmaf(qv, v.y, acc[j4 * 4 + 1]);
                    acc[j4 * 4 + 2] = fmaf(qv, v.z, acc[j4 * 4 + 2]);
                    acc[j4 * 4 + 3] = fmaf(qv, v.w, acc[j4 * 4 + 3]);
                }
            }
            int n = i * 32 + q;
            size_t base = (((size_t)chunk * BATCH + b) * NPTS + n) * CAND + wg * 28;
            float4* outp = (float4*)&p.Dp[base];
#pragma unroll
            for (int j4 = 0; j4 < 7; ++j4)
                outp[j4] = make_float4(acc[j4 * 4], acc[j4 * 4 + 1], acc[j4 * 4 + 2], acc[j4 * 4 + 3]);
        }
    }
    gsync(p.bar, phase, G);
    for (int wk = blockIdx.x; wk < 256 * BATCH; wk += G) {
        __syncthreads();
        select_body<NCH>(wk, p, smem);
    }
    gsync(p.bar, phase, G);
    for (int wk = blockIdx.x; wk < CO * BATCH; wk += G) {
        __syncthreads();
        agg_body<CO, CHOUT>(wk, p, partOut, smem);
    }
    gsync(p.bar, phase, G);
}

// ================================================================ whole network, persistent kernel
__global__ __launch_bounds__(256, 2) void kall(KP p) {
    __shared__ __align__(16) float smem[7168];
    __shared__ float shsc[128];
    __shared__ float shsh[128];
    const int G = gridDim.x;
    int phase = 0;

    for (int wk = blockIdx.x; wk < 204; wk += G) {
        __syncthreads();
        prep_body(wk, p, smem);
    }
    gsync(p.bar, phase, G);

    layer_run<256, 128, 8, 0,   false>(p, p.x,                  256 * 1024, p.wt,          p.wt + 32768,
                                       nullptr, nullptr, nullptr, p.part, smem, shsc, shsh, phase);
    layer_run<128, 128, 4, 128, true >(p, p.xconM,              384 * 1024, p.wt + 65536,  p.wt + 81920,
                                       p.part, p.g0, p.b0, p.part + 512, smem, shsc, shsh, phase);
    layer_run<128, 64,  4, 256, true >(p, p.xconM + 128 * 1024, 384 * 1024, p.wt + 98304,  p.wt + 106496,
                                       p.part + 512, p.g1, p.b1, p.part + 1024, smem, shsc, shsh, phase);
    layer_run<64,  64,  2, 320, true >(p, p.xconM + 256 * 1024, 384 * 1024, p.wt + 114688, p.wt + 118784,
                                       p.part + 1024, p.g2, p.b2, p.part + 1536, smem, shsc, shsh, phase);

    // ---- final GEMM
    {
        float* sc = smem + 4224;
        float* sh = smem + 4608;
        int t = threadIdx.x;
        for (int ch = t; ch < 384; ch += 256) {
            const float* pl; const float* gl; const float* bl; int o, Col;
            if (ch < 128)      { pl = p.part;        gl = p.g0; bl = p.b0; o = ch;       Col = 128; }
            else if (ch < 256) { pl = p.part + 512;  gl = p.g1; bl = p.b1; o = ch - 128; Col = 128; }
            else if (ch < 320) { pl = p.part + 1024; gl = p.g2; bl = p.b2; o = ch - 256; Col = 64;  }
            else               { pl = p.part + 1536; gl = p.g3; bl = p.b3; o = ch - 320; Col = 64;  }
            float s  = pl[o * 2]     + pl[(Col + o) * 2];
            float s2 = pl[o * 2 + 1] + pl[(Col + o) * 2 + 1];
            const float invc = 1.f / 131072.f;
            float mu = s * invc;
            float var = s2 * invc - mu * mu;
            float rs = rsqrtf(var + 1e-5f);
            float scv = gl[o] * rs;
            sc[ch] = scv;
            sh[ch] = bl[o] - mu * scv;
        }
        __syncthreads();
        for (int wk = blockIdx.x; wk < 192; wk += G) {
            __syncthreads();
            final_body(wk, p, smem, sc, sh);
        }
    }
}

extern "C" void kernel_launch(void* const* d_in, const int* in_sizes, int n_in,
                              void* d_out, int out_size, void* d_ws, size_t ws_size,
                              hipStream_t stream) {
    float* ws = (float*)d_ws;
    KP kp;
    kp.x  = (const float*)d_in[0];
    kp.w0 = (const float*)d_in[1];  kp.g0 = (const float*)d_in[2];  kp.b0 = (const float*)d_in[3];
    kp.w1 = (const float*)d_in[4];  kp.g1 = (const float*)d_in[5];  kp.b1 = (const float*)d_in[6];
    kp.w2 = (const float*)d_in[7];  kp.g2 = (const float*)d_in[8];  kp.b2 = (const float*)d_in[9];
    kp.w3 = (const float*)d_in[10]; kp.g3 = (const float*)d_in[11]; kp.b3 = (const float*)d_in[12];
    kp.wl = (const float*)d_in[13];
    kp.xconM = ws;                        // 786432
    kp.A     = kp.xconM + 786432;         // 262144
    kp.Bv    = kp.A + 262144;             // 262144
    kp.sqv   = kp.Bv + 262144;            // 2048
    kp.Dp    = kp.sqv + 2048;             // 8 planes * 458752 = 3670016
    kp.part  = kp.Dp + 3670016;           // 2048
    kp.wt    = kp.part + 2048;            // 270336
    kp.idx   = (int*)(kp.wt + 270336);    // 131072 ints (k-major [b][k][n])
    kp.bar   = kp.idx + 131072;           // barrier counter
    kp.out   = (float*)d_out;

    hipMemsetAsync(kp.bar, 0, sizeof(int), stream);
    kall<<<dim3(512), dim3(256), 0, stream>>>(kp);
}

// Round 14
// 257.322 us; speedup vs baseline: 7.4849x; 7.4849x over previous
//
#include <hip/hip_runtime.h>
#include <math.h>

#define NPTS 1024
#define CAND 224   // 7*32
#define KEFF 64
#define BATCH 2
#define NEGV -1e30f
#define PLANE (BATCH * NPTS * CAND)

// ================================================================ weight prep
__global__ __launch_bounds__(256) void kprep(const float* __restrict__ w0, const float* __restrict__ w1,
                                             const float* __restrict__ w2, const float* __restrict__ w3,
                                             const float* __restrict__ wl, float* __restrict__ wt) {
    __shared__ float tA[32][33];
    __shared__ float tB[32][33];
    int id = blockIdx.x;
    int t = threadIdx.x;
    int row = t >> 5, col = t & 31;
    const float* W = w0; int Cin = 256, Co = 128; float* WtA = wt; float* WtB = wt + 32768;
    int tc = 0, to = 0; bool isWL = false;
    if (id < 32)      { int r = id;      tc = r >> 2; to = r & 3; }
    else if (id < 48) { W = w1; Cin = 128; Co = 128; WtA = wt + 65536;  WtB = wt + 81920;  int r = id - 32; tc = r >> 2; to = r & 3; }
    else if (id < 56) { W = w2; Cin = 128; Co = 64;  WtA = wt + 98304;  WtB = wt + 106496; int r = id - 48; tc = r >> 1; to = r & 1; }
    else if (id < 60) { W = w3; Cin = 64;  Co = 64;  WtA = wt + 114688; WtB = wt + 118784; int r = id - 56; tc = r >> 1; to = r & 1; }
    else { isWL = true; int r = id - 60; tc = r / 12; to = r % 12; }
    if (!isWL) {
#pragma unroll
        for (int r = 0; r < 4; ++r) {
            int o = to * 32 + row + r * 8;
            int c = tc * 32 + col;
            float va = W[(size_t)o * 2 * Cin + c];
            tA[row + r * 8][col] = va;
            tB[row + r * 8][col] = W[(size_t)o * 2 * Cin + Cin + c] - va;
        }
        __syncthreads();
#pragma unroll
        for (int r = 0; r < 4; ++r) {
            int c = tc * 32 + row + r * 8;
            int o = to * 32 + col;
            WtA[(size_t)c * Co + o] = tA[col][row + r * 8];
            WtB[(size_t)c * Co + o] = tB[col][row + r * 8];
        }
    } else {
        float* wlT = wt + 122880;
#pragma unroll
        for (int r = 0; r < 4; ++r) {
            int o = to * 32 + row + r * 8;
            int c = tc * 32 + col;
            tA[row + r * 8][col] = wl[(size_t)o * 384 + c];
        }
        __syncthreads();
#pragma unroll
        for (int r = 0; r < 4; ++r) {
            int c = tc * 32 + row + r * 8;
            int o = to * 32 + col;
            wlT[(size_t)c * 384 + o] = tA[col][row + r * 8];
        }
    }
}

// ================================================================ GEMM (A/Bv/sq) + banded gram partials
struct GP {
    const float* xin; int bstride; int Cin; int Co; int nch; int applyBN;
    const float* WtA; const float* WtB;
    const float* partPrev; const float* gPrev; const float* bePrev;
    float* A; float* Bv; float* sq; float* Dp;
};

__global__ __launch_bounds__(256) void kgemm(GP p) {
    __shared__ float smem[7168];      // roleA: Xs[1024], Wta@1024[2176], Wtb@3200[2176]; roleB: Xc[32][224]
    __shared__ float shsc[128];
    __shared__ float shsh[128];
    int t = threadIdx.x;
    if (p.applyBN && t < p.Cin) {
        const float* pp = p.partPrev;
        float s  = pp[t * 2]     + pp[(p.Cin + t) * 2];
        float s2 = pp[t * 2 + 1] + pp[(p.Cin + t) * 2 + 1];
        const float invc = 1.f / 131072.f;
        float mu = s * invc;
        float var = s2 * invc - mu * mu;
        float rs = rsqrtf(var + 1e-5f);
        float sc = p.gPrev[t] * rs;
        shsc[t] = sc;
        shsh[t] = p.bePrev[t] - mu * sc;
    }
    __syncthreads();
    int nOT = p.Co >> 6;
    int nABx = 32 * nOT * BATCH;
    if ((int)blockIdx.x < nABx) {
        // ---------------- role A: 32n x 64o tile; thread = 4o x 2n
        int id = blockIdx.x;
        int nt = id & 31; int rest = id >> 5;
        int ot = rest % nOT; int b = rest / nOT;
        int tn2 = (t & 15) * 2, to4 = (t >> 4) * 4;
        int n0 = nt * 32, o0 = ot * 64;
        const float* xb = p.xin + (size_t)b * p.bstride + n0;
        float* Xs = smem; float* Wta = smem + 1024; float* Wtb = smem + 3200;
        float2 a2[4], b2[4], s2v;
#pragma unroll
        for (int i = 0; i < 4; ++i) { a2[i] = make_float2(0.f,0.f); b2[i] = make_float2(0.f,0.f); }
        s2v = make_float2(0.f,0.f);
        int xcc0 = t >> 5, xnn = t & 31;   // k<4: cc = xcc0 + k*8
        int wcc0 = t >> 6, woo = t & 63;   // k<8: cc = wcc0 + k*4
        for (int c0 = 0; c0 < p.Cin; c0 += 32) {
            float rx[4], ra[8], rb[8];
#pragma unroll
            for (int k = 0; k < 4; ++k)
                rx[k] = xb[(size_t)(c0 + xcc0 + k * 8) * NPTS + xnn];
#pragma unroll
            for (int k = 0; k < 8; ++k) {
                ra[k] = p.WtA[(size_t)(c0 + wcc0 + k * 4) * p.Co + o0 + woo];
                rb[k] = p.WtB[(size_t)(c0 + wcc0 + k * 4) * p.Co + o0 + woo];
            }
            if (p.applyBN) {
#pragma unroll
                for (int k = 0; k < 4; ++k) {
                    int cc = xcc0 + k * 8;
                    float y = fmaf(rx[k], shsc[c0 + cc], shsh[c0 + cc]);
                    rx[k] = y >= 0.f ? y : 0.2f * y;
                }
            }
            __syncthreads();   // prev-tile compute done before overwrite
#pragma unroll
            for (int k = 0; k < 4; ++k)
                Xs[(xcc0 + k * 8) * 32 + xnn] = rx[k];
#pragma unroll
            for (int k = 0; k < 8; ++k) {
                Wta[(wcc0 + k * 4) * 68 + woo] = ra[k];
                Wtb[(wcc0 + k * 4) * 68 + woo] = rb[k];
            }
            __syncthreads();
#pragma unroll 8
            for (int cc = 0; cc < 32; ++cc) {
                float2 xv = *(const float2*)&Xs[cc * 32 + tn2];
                float4 wa = *(const float4*)&Wta[cc * 68 + to4];
                float4 wb = *(const float4*)&Wtb[cc * 68 + to4];
                s2v.x = fmaf(xv.x, xv.x, s2v.x);
                s2v.y = fmaf(xv.y, xv.y, s2v.y);
                float wav[4] = {wa.x, wa.y, wa.z, wa.w};
                float wbv[4] = {wb.x, wb.y, wb.z, wb.w};
#pragma unroll
                for (int i = 0; i < 4; ++i) {
                    a2[i].x = fmaf(wav[i], xv.x, a2[i].x);
                    a2[i].y = fmaf(wav[i], xv.y, a2[i].y);
                    b2[i].x = fmaf(wbv[i], xv.x, b2[i].x);
                    b2[i].y = fmaf(wbv[i], xv.y, b2[i].y);
                }
            }
        }
        int n = n0 + tn2;
        if (ot == 0 && to4 == 0)
            *(float2*)&p.sq[b * NPTS + n] = s2v;
#pragma unroll
        for (int i = 0; i < 4; ++i) {
            int o = o0 + to4 + i;
            size_t off = ((size_t)(b * p.Co + o)) * NPTS + n;
            *(float2*)&p.A[off] = a2[i];
            *(float2*)&p.Bv[off] = b2[i];
        }
    } else {
        // ---------------- role B: one 32-channel gram partial per block
        int id2 = blockIdx.x - nABx;
        int chunk = id2 % p.nch; int rest = id2 / p.nch;
        int i = rest & 31; int b = rest >> 5;
        int c0 = chunk * 32;
        const float* xb = p.xin + (size_t)b * p.bstride;
        float* Xc = smem;
        int q = t >> 3;
        int wg = t & 7;
        float r[28];
        int rcc[28], rw[28];
#pragma unroll
        for (int k = 0; k < 28; ++k) {
            int e = t + k * 256;
            int cc = e / CAND;
            int w  = e - cc * CAND;
            rcc[k] = cc; rw[k] = w;
            int wb = i - 3 + (w >> 5);
            wb = wb < 0 ? 0 : (wb > 31 ? 31 : wb);
            r[k] = xb[(size_t)(c0 + cc) * NPTS + wb * 32 + (w & 31)];
        }
        if (p.applyBN) {
#pragma unroll
            for (int k = 0; k < 28; ++k) {
                float y = fmaf(r[k], shsc[c0 + rcc[k]], shsh[c0 + rcc[k]]);
                r[k] = y >= 0.f ? y : 0.2f * y;
            }
        }
#pragma unroll
        for (int k = 0; k < 28; ++k)
            Xc[rcc[k] * CAND + rw[k]] = r[k];
        __syncthreads();
        float acc[28];
#pragma unroll
        for (int j = 0; j < 28; ++j) acc[j] = 0.f;
        for (int cc = 0; cc < 32; ++cc) {
            float qv = Xc[cc * CAND + 96 + q];
            const float4* row = (const float4*)&Xc[cc * CAND + wg * 28];
#pragma unroll
            for (int j4 = 0; j4 < 7; ++j4) {
                float4 v = row[j4];
                acc[j4 * 4 + 0] = fmaf(qv, v.x, acc[j4 * 4 + 0]);
                acc[j4 * 4 + 1] = fmaf(qv, v.y, acc[j4 * 4 + 1]);
                acc[j4 * 4 + 2] = fmaf(qv, v.z, acc[j4 * 4 + 2]);
                acc[j4 * 4 + 3] = fmaf(qv, v.w, acc[j4 * 4 + 3]);
            }
        }
        int n = i * 32 + q;
        size_t base = (((size_t)chunk * BATCH + b) * NPTS + n) * CAND + wg * 28;
        float4* outp = (float4*)&p.Dp[base];
#pragma unroll
        for (int j4 = 0; j4 < 7; ++j4)
            outp[j4] = make_float4(acc[j4 * 4], acc[j4 * 4 + 1], acc[j4 * 4 + 2], acc[j4 * 4 + 3]);
    }
}

// ================================================================ top-64 rank selection (64-bit keys); idx k-major
template<int NCH>
__global__ __launch_bounds__(256) void kselect(const float* __restrict__ Dp,
                                               const float* __restrict__ sq,
                                               int* __restrict__ idxo) {
    __shared__ ulonglong2 Dsh2[4][112];
    unsigned long long* Dsh = (unsigned long long*)Dsh2;
    int t = threadIdx.x;
    int wv = t >> 6, l = t & 63;
    int b = blockIdx.y;
    int n = blockIdx.x * 4 + wv;
    int i = n >> 5;
    float sqn = sq[b * NPTS + n];
    float pr[4][NCH];
    float sqw[4];
#pragma unroll
    for (int j = 0; j < 4; ++j) {
        int w = l + 64 * j;
        if (w < CAND) {
            size_t off = ((size_t)b * NPTS + n) * CAND + w;
#pragma unroll
            for (int ch = 0; ch < NCH; ++ch)
                pr[j][ch] = Dp[off + (size_t)ch * PLANE];
            int wb = i - 3 + (w >> 5);
            int wbc = wb < 0 ? 0 : (wb > 31 ? 31 : wb);
            sqw[j] = sq[b * NPTS + wbc * 32 + (w & 31)];
        }
    }
    unsigned long long kj[4];
#pragma unroll
    for (int j = 0; j < 4; ++j) {
        int w = l + 64 * j;
        if (w < CAND) {
            float s = 0.f;
#pragma unroll
            for (int ch = 0; ch < NCH; ++ch) s += pr[j][ch];
            int wb = i - 3 + (w >> 5);
            bool valid = (wb >= 0) && (wb < 32);
            float d = 2.f * s - sqn - sqw[j];
            d = valid ? d : NEGV;
            unsigned u = __float_as_uint(d);
            u ^= ((unsigned)((int)u >> 31)) | 0x80000000u;
            unsigned long long key = ((unsigned long long)u << 8) | (unsigned long long)(255 - w);
            kj[j] = key;
            Dsh[wv * 224 + w] = key;
        } else {
            kj[j] = 0ull;
        }
    }
    __syncthreads();
    int cnt[4] = {0, 0, 0, 0};
    const ulonglong2* row = Dsh2[wv];
#pragma unroll 2
    for (int w2 = 0; w2 < 112; w2 += 4) {
        ulonglong2 k0 = row[w2], k1 = row[w2 + 1], k2 = row[w2 + 2], k3 = row[w2 + 3];
#pragma unroll
        for (int j = 0; j < 4; ++j) {
            unsigned long long kk = kj[j];
            cnt[j] += (int)(k0.x > kk) + (int)(k0.y > kk) + (int)(k1.x > kk) + (int)(k1.y > kk)
                    + (int)(k2.x > kk) + (int)(k2.y > kk) + (int)(k3.x > kk) + (int)(k3.y > kk);
        }
    }
#pragma unroll
    for (int j = 0; j < 4; ++j) {
        int w = l + 64 * j;
        if (w < CAND && cnt[j] < KEFF)
            idxo[((size_t)b * KEFF + cnt[j]) * NPTS + n] = (i - 3) * 32 + w;   // k-major
    }
}

// ================================================================ gather + max/S1/S2 (idx k-major, coalesced)
__global__ __launch_bounds__(256) void kagg(const float* __restrict__ A, const float* __restrict__ Bv,
                                            const int* __restrict__ idx, int Co,
                                            float* __restrict__ xconM, int chOut,
                                            float* __restrict__ part) {
    __shared__ float Ash[NPTS];
    __shared__ float red[256];
    int o = blockIdx.x, b = blockIdx.y, t = threadIdx.x;
    size_t rowoff = ((size_t)(b * Co + o)) * NPTS;
    {
        float rA[4];
#pragma unroll
        for (int r = 0; r < 4; ++r) rA[r] = A[rowoff + r * 256 + t];
#pragma unroll
        for (int r = 0; r < 4; ++r) Ash[r * 256 + t] = rA[r];
    }
    __syncthreads();
    float sum = 0.f, sumsq = 0.f;
    for (int r = 0; r < 4; ++r) {
        int n = r * 256 + t;
        const int* ip = idx + (size_t)b * KEFF * NPTS + n;
        float s1 = 0.f, s2 = 0.f, mx = -3.4e38f;
#pragma unroll
        for (int kb = 0; kb < 4; ++kb) {
            int iv[16];
#pragma unroll
            for (int m = 0; m < 16; ++m)
                iv[m] = ip[(size_t)(kb * 16 + m) * NPTS];
            float av[16];
#pragma unroll
            for (int m = 0; m < 16; ++m) av[m] = Ash[iv[m]];
#pragma unroll
            for (int m = 0; m < 16; m += 4) {
                s1 += av[m] + av[m+1] + av[m+2] + av[m+3];
                s2 += av[m]*av[m] + av[m+1]*av[m+1] + av[m+2]*av[m+2] + av[m+3]*av[m+3];
                mx = fmaxf(mx, fmaxf(fmaxf(av[m], av[m+1]), fmaxf(av[m+2], av[m+3])));
            }
        }
        float bv = Bv[rowoff + n];
        xconM[((size_t)b * 384 + chOut + o) * NPTS + n] = mx + bv;
        sum   += s1 + 64.f * bv;
        sumsq += s2 + 2.f * bv * s1 + 64.f * bv * bv;
    }
    red[t] = sum; __syncthreads();
    for (int s = 128; s > 0; s >>= 1) { if (t < s) red[t] += red[t + s]; __syncthreads(); }
    if (t == 0) part[((size_t)(b * Co + o)) * 2 + 0] = red[0];
    __syncthreads();
    red[t] = sumsq; __syncthreads();
    for (int s = 128; s > 0; s >>= 1) { if (t < s) red[t] += red[t + s]; __syncthreads(); }
    if (t == 0) part[((size_t)(b * Co + o)) * 2 + 1] = red[0];
}

// ================================================================ final GEMM with BN+leaky on load
struct FP {
    const float* part0; const float* part1; const float* part2; const float* part3;
    const float* g0; const float* g1; const float* g2; const float* g3;
    const float* be0; const float* be1; const float* be2; const float* be3;
};

__global__ __launch_bounds__(256) void kfinal(const float* __restrict__ xconM,
                                              const float* __restrict__ wlT, FP p,
                                              float* __restrict__ out) {
    __shared__ float Xs[2048];
    __shared__ float Wl[2176];
    __shared__ float shsc[384];
    __shared__ float shsh[384];
    int t = threadIdx.x;
    for (int ch = t; ch < 384; ch += 256) {
        const float* pl; const float* gl; const float* bl; int o, Col;
        if (ch < 128)      { pl = p.part0; gl = p.g0; bl = p.be0; o = ch;       Col = 128; }
        else if (ch < 256) { pl = p.part1; gl = p.g1; bl = p.be1; o = ch - 128; Col = 128; }
        else if (ch < 320) { pl = p.part2; gl = p.g2; bl = p.be2; o = ch - 256; Col = 64;  }
        else               { pl = p.part3; gl = p.g3; bl = p.be3; o = ch - 320; Col = 64;  }
        float s  = pl[o * 2]     + pl[(Col + o) * 2];
        float s2 = pl[o * 2 + 1] + pl[(Col + o) * 2 + 1];
        const float invc = 1.f / 131072.f;
        float mu = s * invc;
        float var = s2 * invc - mu * mu;
        float rs = rsqrtf(var + 1e-5f);
        float sc = gl[o] * rs;
        shsc[ch] = sc;
        shsh[ch] = bl[o] - mu * sc;
    }
    __syncthreads();
    int tn4 = (t & 15) * 4, to4 = (t >> 4) * 4;
    int n0 = blockIdx.x * 64, o0 = blockIdx.y * 64, b = blockIdx.z;
    int cc0 = t >> 6, nn0 = t & 63;
    float4 acc[4];
#pragma unroll
    for (int i = 0; i < 4; ++i) acc[i] = make_float4(0.f,0.f,0.f,0.f);
    for (int c0 = 0; c0 < 384; c0 += 32) {
        float rx[8], rw[8];
#pragma unroll
        for (int k = 0; k < 8; ++k) {
            int cc = cc0 + k * 4;
            rx[k] = xconM[((size_t)b * 384 + c0 + cc) * NPTS + n0 + nn0];
            rw[k] = wlT[(size_t)(c0 + cc) * 384 + o0 + nn0];
        }
#pragma unroll
        for (int k = 0; k < 8; ++k) {
            int cc = cc0 + k * 4;
            float y = fmaf(rx[k], shsc[c0 + cc], shsh[c0 + cc]);
            rx[k] = y >= 0.f ? y : 0.2f * y;
        }
        __syncthreads();
#pragma unroll
        for (int k = 0; k < 8; ++k) {
            int cc = cc0 + k * 4;
            Xs[cc * 64 + nn0] = rx[k];
            Wl[cc * 68 + nn0] = rw[k];
        }
        __syncthreads();
#pragma unroll 4
        for (int cc = 0; cc < 32; ++cc) {
            float4 xv = *(const float4*)&Xs[cc * 64 + tn4];
            float4 wv = *(const float4*)&Wl[cc * 68 + to4];
            float wvv[4] = {wv.x, wv.y, wv.z, wv.w};
#pragma unroll
            for (int i = 0; i < 4; ++i) {
                acc[i].x = fmaf(wvv[i], xv.x, acc[i].x);
                acc[i].y = fmaf(wvv[i], xv.y, acc[i].y);
                acc[i].z = fmaf(wvv[i], xv.z, acc[i].z);
                acc[i].w = fmaf(wvv[i], xv.w, acc[i].w);
            }
        }
    }
#pragma unroll
    for (int i = 0; i < 4; ++i)
        *(float4*)&out[((size_t)b * 384 + o0 + to4 + i) * NPTS + n0 + tn4] = acc[i];
}

extern "C" void kernel_launch(void* const* d_in, const int* in_sizes, int n_in,
                              void* d_out, int out_size, void* d_ws, size_t ws_size,
                              hipStream_t stream) {
    const float* x  = (const float*)d_in[0];
    const float* w[4]  = {(const float*)d_in[1], (const float*)d_in[4], (const float*)d_in[7], (const float*)d_in[10]};
    const float* g[4]  = {(const float*)d_in[2], (const float*)d_in[5], (const float*)d_in[8], (const float*)d_in[11]};
    const float* be[4] = {(const float*)d_in[3], (const float*)d_in[6], (const float*)d_in[9], (const float*)d_in[12]};
    const float* wl = (const float*)d_in[13];

    float* ws    = (float*)d_ws;
    float* xconM = ws;                       // 786432
    float* A     = xconM + 786432;           // 262144
    float* Bv    = A + 262144;               // 262144
    float* sq    = Bv + 262144;              // 2048
    float* Dp    = sq + 2048;                // 8 planes * 458752 = 3670016
    float* part  = Dp + 3670016;             // 2048
    float* wt    = part + 2048;              // 270336
    int*   idx   = (int*)(wt + 270336);      // 131072 ints (k-major: [b][k][n])

    kprep<<<204, 256, 0, stream>>>(w[0], w[1], w[2], w[3], wl, wt);

    struct LC { const float* xin; int bstride; int Cin; int Co; int nch; int chOut;
                const float* wtA; const float* wtB; };
    LC L[4] = {
        { x,                  256 * 1024, 256, 128, 8, 0,   wt,          wt + 32768  },
        { xconM,              384 * 1024, 128, 128, 4, 128, wt + 65536,  wt + 81920  },
        { xconM + 128 * 1024, 384 * 1024, 128, 64,  4, 256, wt + 98304,  wt + 106496 },
        { xconM + 256 * 1024, 384 * 1024, 64,  64,  2, 320, wt + 114688, wt + 118784 },
    };

    for (int l = 0; l < 4; ++l) {
        GP gp;
        gp.xin = L[l].xin; gp.bstride = L[l].bstride; gp.Cin = L[l].Cin; gp.Co = L[l].Co;
        gp.nch = L[l].nch; gp.applyBN = (l > 0);
        gp.WtA = L[l].wtA; gp.WtB = L[l].wtB;
        gp.partPrev = (l > 0) ? part + (l - 1) * 512 : nullptr;
        gp.gPrev = (l > 0) ? g[l - 1] : nullptr;
        gp.bePrev = (l > 0) ? be[l - 1] : nullptr;
        gp.A = A; gp.Bv = Bv; gp.sq = sq; gp.Dp = Dp;
        int nAB = 32 * (L[l].Co >> 6) * BATCH;
        int nDist = L[l].nch * 32 * BATCH;
        kgemm<<<nAB + nDist, 256, 0, stream>>>(gp);
        if (L[l].nch == 8)      kselect<8><<<dim3(NPTS / 4, BATCH), 256, 0, stream>>>(Dp, sq, idx);
        else if (L[l].nch == 4) kselect<4><<<dim3(NPTS / 4, BATCH), 256, 0, stream>>>(Dp, sq, idx);
        else                    kselect<2><<<dim3(NPTS / 4, BATCH), 256, 0, stream>>>(Dp, sq, idx);
        kagg<<<dim3(L[l].Co, BATCH), 256, 0, stream>>>(A, Bv, idx, L[l].Co, xconM, L[l].chOut, part + l * 512);
    }

    FP fp;
    fp.part0 = part; fp.part1 = part + 512; fp.part2 = part + 1024; fp.part3 = part + 1536;
    fp.g0 = g[0]; fp.g1 = g[1]; fp.g2 = g[2]; fp.g3 = g[3];
    fp.be0 = be[0]; fp.be1 = be[1]; fp.be2 = be[2]; fp.be3 = be[3];
    kfinal<<<dim3(16, 6, BATCH), 256, 0, stream>>>(xconM, wt + 122880, fp, (float*)d_out);
}